// Round 1
// baseline (917.868 us; speedup 1.0000x reference)
//
#include <hip/hip_runtime.h>

// ProtoNet: out[q][n] = -|| (xq[q]@W + b) - proto[n] ||^2
// proto[n] = (sum_{s: ys==n} xs[s]) @ W / max(cnt,1) + cnt*b/max(cnt,1)
// Decomposition: dist = qnorm[q] + pnorm[n] - 2*cross[q][n]; out = 2*cross - qnorm - pnorm.

typedef __attribute__((ext_vector_type(8))) short short8;
typedef __attribute__((ext_vector_type(4))) float floatx4;

#define S_ROWS 1024
#define F_DIM  2048
#define D_DIM  512
#define NWAY   64
#define Q_ROWS 16384

// ---- workspace layout (bytes) ----
#define WT_OFF     0u          // bf16 W^T [512][2048]          2,097,152 B
#define ZQ_OFF     2097152u    // bf16 z_q [16384][512]        16,777,216 B
#define CSUM_OFF   18874368u   // f32 class sums [64][2048]       524,288 B
#define PROTO_OFF  19398656u   // bf16 proto [64][512]             65,536 B
#define QNORM_OFF  19464192u   // f32 qnorm [16384]                65,536 B
#define COUNTS_OFF 19529728u   // f32 counts [64]                     256 B
#define PNORM_OFF  19529984u   // f32 pnorm [64]                      256 B
#define ORDER_OFF  19530240u   // i32 order [1024]                  4,096 B
#define STARTS_OFF 19534336u   // i32 starts [65]                     512 B

static __device__ __forceinline__ unsigned short f2bf(float f) {
  unsigned int u = __float_as_uint(f);
  u += 0x7FFF + ((u >> 16) & 1);   // RNE
  return (unsigned short)(u >> 16);
}
static __device__ __forceinline__ float bf2f(unsigned short s) {
  return __uint_as_float(((unsigned int)s) << 16);
}

// ---- K0a: transpose W [2048][512] f32 -> Wt [512][2048] bf16; zero qnorm ----
__global__ __launch_bounds__(256) void k0_transpose(const float* __restrict__ W,
                                                    unsigned short* __restrict__ Wt,
                                                    float* __restrict__ qnorm) {
  __shared__ unsigned short t[64][65];
  int bx = blockIdx.x;
  int f0 = (bx >> 3) << 6;   // 32 f-tiles
  int d0 = (bx & 7) << 6;    // 8 d-tiles
  for (int j = 0; j < 16; j++) {
    int lin = j * 256 + threadIdx.x;
    int fl = lin >> 6, dl = lin & 63;
    t[fl][dl] = f2bf(W[(size_t)(f0 + fl) * 512 + d0 + dl]);
  }
  __syncthreads();
  for (int j = 0; j < 16; j++) {
    int lin = j * 256 + threadIdx.x;
    int dl = lin >> 6, fl = lin & 63;
    Wt[(size_t)(d0 + dl) * 2048 + f0 + fl] = t[fl][dl];
  }
  int base = bx * 64;
  if (threadIdx.x < 64) qnorm[base + threadIdx.x] = 0.f;
}

// ---- K0b: sort support indices by class (single block) ----
__global__ __launch_bounds__(256) void k0_sort(const int* __restrict__ ys,
                                               int* __restrict__ order,
                                               int* __restrict__ starts,
                                               float* __restrict__ counts) {
  __shared__ int lys[S_ROWS];
  __shared__ int cnt[NWAY];
  __shared__ int st[NWAY + 1];
  int tid = threadIdx.x;
  for (int j = tid; j < S_ROWS; j += 256) lys[j] = ys[j];
  __syncthreads();
  if (tid < NWAY) {
    int c = 0;
    for (int s = 0; s < S_ROWS; s++) c += (lys[s] == tid);
    cnt[tid] = c;
  }
  __syncthreads();
  if (tid == 0) {
    int a = 0;
    for (int c = 0; c < NWAY; c++) { st[c] = a; a += cnt[c]; }
    st[NWAY] = a;
  }
  __syncthreads();
  if (tid < NWAY) {
    int w = st[tid];
    for (int s = 0; s < S_ROWS; s++)
      if (lys[s] == tid) order[w++] = s;
    counts[tid] = (float)cnt[tid];
  }
  if (tid < NWAY + 1) starts[tid] = st[tid];
}

// ---- K1: class sums csum[c][f] = sum over sorted segment ----
__global__ __launch_bounds__(256) void k1_csum(const float* __restrict__ xs,
                                               const int* __restrict__ order,
                                               const int* __restrict__ starts,
                                               float* __restrict__ csum) {
  __shared__ int lord[S_ROWS];
  __shared__ int lst[NWAY + 1];
  int tid = threadIdx.x;
  int f0 = blockIdx.x * 256;
  for (int j = tid; j < S_ROWS; j += 256) lord[j] = order[j];
  if (tid < NWAY + 1) lst[tid] = starts[tid];
  __syncthreads();
  for (int c = 0; c < NWAY; c++) {
    float a = 0.f;
    int e = lst[c + 1];
    for (int i = lst[c]; i < e; i++)
      a += xs[(size_t)lord[i] * F_DIM + f0 + tid];
    csum[(size_t)c * F_DIM + f0 + tid] = a;
  }
}

// ---- K2: proto[n][d] = (csum[n]@W + cnt*b)/max(cnt,1); pnorm; bf16 proto ----
__global__ __launch_bounds__(256) void k2_proto(const float* __restrict__ W,
                                                const float* __restrict__ b,
                                                const float* __restrict__ csum,
                                                const float* __restrict__ counts,
                                                unsigned short* __restrict__ proto_bf,
                                                float* __restrict__ pnorm) {
  __shared__ float cs[F_DIM];
  __shared__ float red[256];
  int n = blockIdx.x, tid = threadIdx.x;
  for (int j = 0; j < F_DIM / 256; j++) cs[j * 256 + tid] = csum[(size_t)n * F_DIM + j * 256 + tid];
  __syncthreads();
  float cntv = counts[n];
  float inv = 1.f / fmaxf(cntv, 1.f);
  float a0 = 0.f, a1 = 0.f;
#pragma unroll 8
  for (int f = 0; f < F_DIM; f++) {
    float v = cs[f];
    a0 += v * W[(size_t)f * 512 + tid];
    a1 += v * W[(size_t)f * 512 + tid + 256];
  }
  float p0 = (a0 + cntv * b[tid]) * inv;
  float p1 = (a1 + cntv * b[tid + 256]) * inv;
  unsigned short h0 = f2bf(p0), h1 = f2bf(p1);
  proto_bf[(size_t)n * 512 + tid] = h0;
  proto_bf[(size_t)n * 512 + tid + 256] = h1;
  float q0 = bf2f(h0), q1 = bf2f(h1);
  red[tid] = q0 * q0 + q1 * q1;
  __syncthreads();
  for (int s = 128; s > 0; s >>= 1) {
    if (tid < s) red[tid] += red[tid + s];
    __syncthreads();
  }
  if (tid == 0) pnorm[n] = red[0];
}

// ---- K3: z_q = xq@W + b (bf16 MFMA, 128x128 tile, BK=32), fused qnorm ----
__global__ __launch_bounds__(256) void k3_gemm1(const float* __restrict__ xq,
                                                const unsigned short* __restrict__ Wt,
                                                const float* __restrict__ b,
                                                unsigned short* __restrict__ zq,
                                                float* __restrict__ qnorm) {
  __shared__ unsigned short lA[128 * 32];
  __shared__ unsigned short lB[128 * 32];
  int tid = threadIdx.x;
  int bx = blockIdx.x;
  int n0 = (bx & 3) * 128;
  int m0 = (bx >> 2) * 128;
  int wave = tid >> 6, lane = tid & 63;
  int wm = (wave & 1) * 64, wn = (wave >> 1) * 64;
  int lrow = lane & 15, lquad = lane >> 4;

  floatx4 acc[4][4];
#pragma unroll
  for (int i = 0; i < 4; i++)
#pragma unroll
    for (int j = 0; j < 4; j++) acc[i][j] = (floatx4){0.f, 0.f, 0.f, 0.f};

  int a_row = tid >> 3, a_kq = tid & 7;        // A: 4 passes of 32 rows, 8 float4/row
  int b_n = tid >> 2, b_k8 = (tid & 3) * 8;    // B: 2 passes of 64 rows, 4x16B/row

  for (int k0 = 0; k0 < F_DIM; k0 += 32) {
#pragma unroll
    for (int p = 0; p < 4; p++) {
      int row = p * 32 + a_row;
      float4 v = *(const float4*)&xq[(size_t)(m0 + row) * F_DIM + k0 + a_kq * 4];
      ushort4 w;
      w.x = f2bf(v.x); w.y = f2bf(v.y); w.z = f2bf(v.z); w.w = f2bf(v.w);
      *(ushort4*)&lA[row * 32 + a_kq * 4] = w;
    }
#pragma unroll
    for (int p = 0; p < 2; p++) {
      int n = p * 64 + b_n;
      *(float4*)&lB[n * 32 + b_k8] = *(const float4*)&Wt[(size_t)(n0 + n) * 2048 + k0 + b_k8];
    }
    __syncthreads();
    short8 af[4], bfr[4];
#pragma unroll
    for (int i = 0; i < 4; i++) af[i] = *(const short8*)&lA[(wm + i * 16 + lrow) * 32 + lquad * 8];
#pragma unroll
    for (int j = 0; j < 4; j++) bfr[j] = *(const short8*)&lB[(wn + j * 16 + lrow) * 32 + lquad * 8];
#pragma unroll
    for (int i = 0; i < 4; i++)
#pragma unroll
      for (int j = 0; j < 4; j++)
        acc[i][j] = __builtin_amdgcn_mfma_f32_16x16x32_bf16(af[i], bfr[j], acc[i][j], 0, 0, 0);
    __syncthreads();
  }

  // epilogue: z = acc + b[col]; store bf16; row-norm via quad shuffle + atomics
#pragma unroll
  for (int i = 0; i < 4; i++) {
    float rn[4] = {0.f, 0.f, 0.f, 0.f};
#pragma unroll
    for (int j = 0; j < 4; j++) {
      int col = n0 + wn + j * 16 + lrow;
      float bb = b[col];
#pragma unroll
      for (int r = 0; r < 4; r++) {
        int row = m0 + wm + i * 16 + lquad * 4 + r;
        float v = acc[i][j][r] + bb;
        unsigned short h = f2bf(v);
        zq[(size_t)row * 512 + col] = h;
        float vq = bf2f(h);
        rn[r] += vq * vq;
      }
    }
#pragma unroll
    for (int r = 0; r < 4; r++) {
      float s = rn[r];
      s += __shfl_xor(s, 1, 16);
      s += __shfl_xor(s, 2, 16);
      s += __shfl_xor(s, 4, 16);
      s += __shfl_xor(s, 8, 16);
      if (lrow == 0) {
        int row = m0 + wm + i * 16 + lquad * 4 + r;
        atomicAdd(&qnorm[row], s);
      }
    }
  }
}

// ---- K4: cross = zq @ proto^T (128x64 tile), out = 2*cross - qnorm - pnorm ----
__global__ __launch_bounds__(256) void k4_gemm2(const unsigned short* __restrict__ zq,
                                                const unsigned short* __restrict__ proto_bf,
                                                const float* __restrict__ qnorm,
                                                const float* __restrict__ pnorm,
                                                float* __restrict__ out) {
  __shared__ unsigned short lA[128 * 32];
  __shared__ unsigned short lB[64 * 32];
  int tid = threadIdx.x;
  int r0 = blockIdx.x * 128;
  int wave = tid >> 6, lane = tid & 63;
  int lrow = lane & 15, lquad = lane >> 4;

  floatx4 acc[2][4];
#pragma unroll
  for (int i = 0; i < 2; i++)
#pragma unroll
    for (int j = 0; j < 4; j++) acc[i][j] = (floatx4){0.f, 0.f, 0.f, 0.f};

  int a_n = tid >> 2, a_k8 = (tid & 3) * 8;

  for (int k0 = 0; k0 < 512; k0 += 32) {
#pragma unroll
    for (int p = 0; p < 2; p++) {
      int row = p * 64 + a_n;
      *(float4*)&lA[row * 32 + a_k8] = *(const float4*)&zq[(size_t)(r0 + row) * 512 + k0 + a_k8];
    }
    *(float4*)&lB[a_n * 32 + a_k8] = *(const float4*)&proto_bf[(size_t)a_n * 512 + k0 + a_k8];
    __syncthreads();
    short8 af[2], bfr[4];
#pragma unroll
    for (int i = 0; i < 2; i++) af[i] = *(const short8*)&lA[(wave * 32 + i * 16 + lrow) * 32 + lquad * 8];
#pragma unroll
    for (int j = 0; j < 4; j++) bfr[j] = *(const short8*)&lB[(j * 16 + lrow) * 32 + lquad * 8];
#pragma unroll
    for (int i = 0; i < 2; i++)
#pragma unroll
      for (int j = 0; j < 4; j++)
        acc[i][j] = __builtin_amdgcn_mfma_f32_16x16x32_bf16(af[i], bfr[j], acc[i][j], 0, 0, 0);
    __syncthreads();
  }

#pragma unroll
  for (int i = 0; i < 2; i++) {
#pragma unroll
    for (int j = 0; j < 4; j++) {
      int col = j * 16 + lrow;
      float pn = pnorm[col];
#pragma unroll
      for (int r = 0; r < 4; r++) {
        int row = r0 + wave * 32 + i * 16 + lquad * 4 + r;
        out[(size_t)row * 64 + col] = 2.f * acc[i][j][r] - qnorm[row] - pn;
      }
    }
  }
}

extern "C" void kernel_launch(void* const* d_in, const int* in_sizes, int n_in,
                              void* d_out, int out_size, void* d_ws, size_t ws_size,
                              hipStream_t stream) {
  const float* xs = (const float*)d_in[0];
  const int* ys = (const int*)d_in[1];
  const float* xq = (const float*)d_in[2];
  const float* W = (const float*)d_in[3];
  const float* b = (const float*)d_in[4];
  float* out = (float*)d_out;
  char* ws = (char*)d_ws;

  unsigned short* Wt = (unsigned short*)(ws + WT_OFF);
  unsigned short* zq = (unsigned short*)(ws + ZQ_OFF);
  float* csum = (float*)(ws + CSUM_OFF);
  unsigned short* proto_bf = (unsigned short*)(ws + PROTO_OFF);
  float* qnorm = (float*)(ws + QNORM_OFF);
  float* counts = (float*)(ws + COUNTS_OFF);
  float* pnorm = (float*)(ws + PNORM_OFF);
  int* order = (int*)(ws + ORDER_OFF);
  int* starts = (int*)(ws + STARTS_OFF);

  k0_transpose<<<256, 256, 0, stream>>>(W, Wt, qnorm);
  k0_sort<<<1, 256, 0, stream>>>(ys, order, starts, counts);
  k1_csum<<<8, 256, 0, stream>>>(xs, order, starts, csum);
  k2_proto<<<64, 256, 0, stream>>>(W, b, csum, counts, proto_bf, pnorm);
  k3_gemm1<<<512, 256, 0, stream>>>(xq, Wt, b, zq, qnorm);
  k4_gemm2<<<128, 256, 0, stream>>>(zq, proto_bf, qnorm, pnorm, out);
}

// Round 2
// 378.996 us; speedup vs baseline: 2.4218x; 2.4218x over previous
//
#include <hip/hip_runtime.h>

// ProtoNet: out[q][n] = -|| (xq[q]@W + b) - proto[n] ||^2
// proto[n] = (sum_{s: ys==n} xs[s]) @ W / max(cnt,1) + cnt*b/max(cnt,1)
// dist = qnorm[q] + pnorm[n] - 2*cross[q][n]; out = 2*cross - qnorm - pnorm.

typedef __attribute__((ext_vector_type(8))) short short8;
typedef __attribute__((ext_vector_type(4))) float floatx4;

#define S_ROWS 1024
#define F_DIM  2048
#define D_DIM  512
#define NWAY   64
#define Q_ROWS 16384

static __device__ __forceinline__ unsigned short f2bf(float f) {
  unsigned int u = __float_as_uint(f);
  u += 0x7FFF + ((u >> 16) & 1);   // RNE
  return (unsigned short)(u >> 16);
}
static __device__ __forceinline__ float bf2f(unsigned short s) {
  return __uint_as_float(((unsigned int)s) << 16);
}

// async global->LDS, 16B per lane. LDS dest = wave-uniform base + lane*16.
static __device__ __forceinline__ void load_lds16(const unsigned short* g, unsigned short* l) {
  __builtin_amdgcn_global_load_lds((const __attribute__((address_space(1))) unsigned int*)g,
                                   (__attribute__((address_space(3))) unsigned int*)l,
                                   16, 0, 0);
}

// ---- K0a: transpose W [2048][512] f32 -> Wt [512][2048] bf16; zero qnorm ----
__global__ __launch_bounds__(256) void k0_transpose(const float* __restrict__ W,
                                                    unsigned short* __restrict__ Wt,
                                                    float* __restrict__ qnorm) {
  __shared__ unsigned short t[64][65];
  int bx = blockIdx.x;
  int f0 = (bx >> 3) << 6;   // 32 f-tiles
  int d0 = (bx & 7) << 6;    // 8 d-tiles
  for (int j = 0; j < 16; j++) {
    int lin = j * 256 + threadIdx.x;
    int fl = lin >> 6, dl = lin & 63;
    t[fl][dl] = f2bf(W[(size_t)(f0 + fl) * 512 + d0 + dl]);
  }
  __syncthreads();
  for (int j = 0; j < 16; j++) {
    int lin = j * 256 + threadIdx.x;
    int dl = lin >> 6, fl = lin & 63;
    Wt[(size_t)(d0 + dl) * 2048 + f0 + fl] = t[fl][dl];
  }
  int base = bx * 64;
  if (threadIdx.x < 64) qnorm[base + threadIdx.x] = 0.f;
}

// ---- K0b: bin support indices by class via LDS atomics (single block) ----
__global__ __launch_bounds__(256) void k0_sort(const int* __restrict__ ys,
                                               int* __restrict__ order,
                                               int* __restrict__ starts,
                                               float* __restrict__ counts,
                                               float* __restrict__ pnorm) {
  __shared__ int cnt[NWAY];
  __shared__ int st[NWAY + 1];
  __shared__ int wp[NWAY];
  int tid = threadIdx.x;
  if (tid < NWAY) cnt[tid] = 0;
  __syncthreads();
  for (int j = tid; j < S_ROWS; j += 256) atomicAdd(&cnt[ys[j]], 1);
  __syncthreads();
  if (tid == 0) {
    int a = 0;
    for (int c = 0; c < NWAY; c++) { st[c] = a; wp[c] = a; a += cnt[c]; }
    st[NWAY] = a;
  }
  __syncthreads();
  for (int j = tid; j < S_ROWS; j += 256) {
    int c = ys[j];
    int p = atomicAdd(&wp[c], 1);
    order[p] = j;
  }
  if (tid < NWAY) { counts[tid] = (float)cnt[tid]; pnorm[tid] = 0.f; }
  if (tid < NWAY + 1) starts[tid] = st[tid];
}

// ---- K1: class sums. grid = 64 classes x 2 f-tiles; float4 per thread ----
__global__ __launch_bounds__(256) void k1_csum(const float* __restrict__ xs,
                                               const int* __restrict__ order,
                                               const int* __restrict__ starts,
                                               float* __restrict__ csum) {
  __shared__ int lord[S_ROWS];
  int c = blockIdx.x >> 1;
  int tid = threadIdx.x;
  int s = starts[c], e = starts[c + 1];
  int len = e - s;
  for (int j = tid; j < len; j += 256) lord[j] = order[s + j];
  __syncthreads();
  int f0 = (blockIdx.x & 1) * 1024 + tid * 4;
  float4 a = {0.f, 0.f, 0.f, 0.f};
  for (int i = 0; i < len; i++) {
    float4 v = *(const float4*)&xs[(size_t)lord[i] * F_DIM + f0];
    a.x += v.x; a.y += v.y; a.z += v.z; a.w += v.w;
  }
  *(float4*)&csum[(size_t)c * F_DIM + f0] = a;
}

// ---- K2: proto = (csum@W + cnt*b)/max(cnt,1); pnorm; bf16 proto.
//      grid = 64 classes x 2 d-halves ----
__global__ __launch_bounds__(256) void k2_proto(const float* __restrict__ W,
                                                const float* __restrict__ b,
                                                const float* __restrict__ csum,
                                                const float* __restrict__ counts,
                                                unsigned short* __restrict__ proto_bf,
                                                float* __restrict__ pnorm) {
  __shared__ float cs[F_DIM];
  __shared__ float red[256];
  int n = blockIdx.x >> 1;
  int dh = (blockIdx.x & 1) * 256;
  int tid = threadIdx.x;
  for (int j = 0; j < F_DIM / 256; j++)
    cs[j * 256 + tid] = csum[(size_t)n * F_DIM + j * 256 + tid];
  __syncthreads();
  float cntv = counts[n];
  float inv = 1.f / fmaxf(cntv, 1.f);
  float a0 = 0.f;
#pragma unroll 8
  for (int f = 0; f < F_DIM; f++)
    a0 += cs[f] * W[(size_t)f * 512 + dh + tid];
  float p0 = (a0 + cntv * b[dh + tid]) * inv;
  unsigned short h0 = f2bf(p0);
  proto_bf[(size_t)n * 512 + dh + tid] = h0;
  float q0 = bf2f(h0);
  red[tid] = q0 * q0;
  __syncthreads();
  for (int s = 128; s > 0; s >>= 1) {
    if (tid < s) red[tid] += red[tid + s];
    __syncthreads();
  }
  if (tid == 0) atomicAdd(&pnorm[n], red[0]);
}

// ---- Kcvt: xq f32 -> bf16, 8 elems/thread ----
__global__ __launch_bounds__(256) void k_cvt(const float* __restrict__ xq,
                                             unsigned short* __restrict__ xqb) {
  size_t i = ((size_t)blockIdx.x * 256 + threadIdx.x) * 8;
  float4 v0 = *(const float4*)&xq[i];
  float4 v1 = *(const float4*)&xq[i + 4];
  ushort4 w0, w1;
  w0.x = f2bf(v0.x); w0.y = f2bf(v0.y); w0.z = f2bf(v0.z); w0.w = f2bf(v0.w);
  w1.x = f2bf(v1.x); w1.y = f2bf(v1.y); w1.z = f2bf(v1.z); w1.w = f2bf(v1.w);
  *(ushort4*)&xqb[i] = w0;
  *(ushort4*)&xqb[i + 4] = w1;
}

// ---- K3 fast: z_q = xqb@Wt^T + b, bf16 MFMA 128x128xBK32, global_load_lds staging ----
__global__ __launch_bounds__(256) void k3_gemm1_fast(const unsigned short* __restrict__ xqb,
                                                     const unsigned short* __restrict__ Wt,
                                                     const float* __restrict__ b,
                                                     unsigned short* __restrict__ zq,
                                                     float* __restrict__ qnorm) {
  __shared__ __align__(16) unsigned short lA[128 * 32];
  __shared__ __align__(16) unsigned short lB[128 * 32];
  int tid = threadIdx.x;
  int bx = blockIdx.x;
  int n0 = (bx & 3) * 128;
  int m0 = (bx >> 2) * 128;
  int wave = tid >> 6, lane = tid & 63;
  int wm = (wave & 1) * 64, wn = (wave >> 1) * 64;
  int lrow = lane & 15, lquad = lane >> 4;

  floatx4 acc[4][4];
#pragma unroll
  for (int i = 0; i < 4; i++)
#pragma unroll
    for (int j = 0; j < 4; j++) acc[i][j] = (floatx4){0.f, 0.f, 0.f, 0.f};

  int c0 = wave * 64 + lane;      // base chunk id; chunk covers 16B = 8 halfs

  for (int k0 = 0; k0 < F_DIM; k0 += 32) {
#pragma unroll
    for (int i = 0; i < 2; i++) {
      int c = i * 256 + c0;
      int row = c >> 2, k8 = (c & 3) * 8;
      load_lds16(&xqb[(size_t)(m0 + row) * F_DIM + k0 + k8],
                 &lA[(size_t)(i * 256 + wave * 64) * 8]);
      load_lds16(&Wt[(size_t)(n0 + row) * F_DIM + k0 + k8],
                 &lB[(size_t)(i * 256 + wave * 64) * 8]);
    }
    __syncthreads();
    short8 af[4], bfr[4];
#pragma unroll
    for (int i = 0; i < 4; i++) af[i] = *(const short8*)&lA[(wm + i * 16 + lrow) * 32 + lquad * 8];
#pragma unroll
    for (int j = 0; j < 4; j++) bfr[j] = *(const short8*)&lB[(wn + j * 16 + lrow) * 32 + lquad * 8];
#pragma unroll
    for (int i = 0; i < 4; i++)
#pragma unroll
      for (int j = 0; j < 4; j++)
        acc[i][j] = __builtin_amdgcn_mfma_f32_16x16x32_bf16(af[i], bfr[j], acc[i][j], 0, 0, 0);
    __syncthreads();
  }

#pragma unroll
  for (int i = 0; i < 4; i++) {
    float rn[4] = {0.f, 0.f, 0.f, 0.f};
#pragma unroll
    for (int j = 0; j < 4; j++) {
      int col = n0 + wn + j * 16 + lrow;
      float bb = b[col];
#pragma unroll
      for (int r = 0; r < 4; r++) {
        int row = m0 + wm + i * 16 + lquad * 4 + r;
        float v = acc[i][j][r] + bb;
        unsigned short h = f2bf(v);
        zq[(size_t)row * 512 + col] = h;
        float vq = bf2f(h);
        rn[r] += vq * vq;
      }
    }
#pragma unroll
    for (int r = 0; r < 4; r++) {
      float s = rn[r];
      s += __shfl_xor(s, 1, 16);
      s += __shfl_xor(s, 2, 16);
      s += __shfl_xor(s, 4, 16);
      s += __shfl_xor(s, 8, 16);
      if (lrow == 0) {
        int row = m0 + wm + i * 16 + lquad * 4 + r;
        atomicAdd(&qnorm[row], s);
      }
    }
  }
}

// ---- K3 fallback: f32 A with in-kernel conversion (used if ws too small) ----
__global__ __launch_bounds__(256) void k3_gemm1(const float* __restrict__ xq,
                                                const unsigned short* __restrict__ Wt,
                                                const float* __restrict__ b,
                                                unsigned short* __restrict__ zq,
                                                float* __restrict__ qnorm) {
  __shared__ unsigned short lA[128 * 32];
  __shared__ unsigned short lB[128 * 32];
  int tid = threadIdx.x;
  int bx = blockIdx.x;
  int n0 = (bx & 3) * 128;
  int m0 = (bx >> 2) * 128;
  int wave = tid >> 6, lane = tid & 63;
  int wm = (wave & 1) * 64, wn = (wave >> 1) * 64;
  int lrow = lane & 15, lquad = lane >> 4;

  floatx4 acc[4][4];
#pragma unroll
  for (int i = 0; i < 4; i++)
#pragma unroll
    for (int j = 0; j < 4; j++) acc[i][j] = (floatx4){0.f, 0.f, 0.f, 0.f};

  int a_row = tid >> 3, a_kq = tid & 7;
  int b_n = tid >> 2, b_k8 = (tid & 3) * 8;

  for (int k0 = 0; k0 < F_DIM; k0 += 32) {
#pragma unroll
    for (int p = 0; p < 4; p++) {
      int row = p * 32 + a_row;
      float4 v = *(const float4*)&xq[(size_t)(m0 + row) * F_DIM + k0 + a_kq * 4];
      ushort4 w;
      w.x = f2bf(v.x); w.y = f2bf(v.y); w.z = f2bf(v.z); w.w = f2bf(v.w);
      *(ushort4*)&lA[row * 32 + a_kq * 4] = w;
    }
#pragma unroll
    for (int p = 0; p < 2; p++) {
      int n = p * 64 + b_n;
      *(float4*)&lB[n * 32 + b_k8] = *(const float4*)&Wt[(size_t)(n0 + n) * 2048 + k0 + b_k8];
    }
    __syncthreads();
    short8 af[4], bfr[4];
#pragma unroll
    for (int i = 0; i < 4; i++) af[i] = *(const short8*)&lA[(wm + i * 16 + lrow) * 32 + lquad * 8];
#pragma unroll
    for (int j = 0; j < 4; j++) bfr[j] = *(const short8*)&lB[(wn + j * 16 + lrow) * 32 + lquad * 8];
#pragma unroll
    for (int i = 0; i < 4; i++)
#pragma unroll
      for (int j = 0; j < 4; j++)
        acc[i][j] = __builtin_amdgcn_mfma_f32_16x16x32_bf16(af[i], bfr[j], acc[i][j], 0, 0, 0);
    __syncthreads();
  }

#pragma unroll
  for (int i = 0; i < 4; i++) {
    float rn[4] = {0.f, 0.f, 0.f, 0.f};
#pragma unroll
    for (int j = 0; j < 4; j++) {
      int col = n0 + wn + j * 16 + lrow;
      float bb = b[col];
#pragma unroll
      for (int r = 0; r < 4; r++) {
        int row = m0 + wm + i * 16 + lquad * 4 + r;
        float v = acc[i][j][r] + bb;
        unsigned short h = f2bf(v);
        zq[(size_t)row * 512 + col] = h;
        float vq = bf2f(h);
        rn[r] += vq * vq;
      }
    }
#pragma unroll
    for (int r = 0; r < 4; r++) {
      float s = rn[r];
      s += __shfl_xor(s, 1, 16);
      s += __shfl_xor(s, 2, 16);
      s += __shfl_xor(s, 4, 16);
      s += __shfl_xor(s, 8, 16);
      if (lrow == 0) {
        int row = m0 + wm + i * 16 + lquad * 4 + r;
        atomicAdd(&qnorm[row], s);
      }
    }
  }
}

// ---- K4: cross = zq @ proto^T; out = 2*cross - qnorm - pnorm ----
__global__ __launch_bounds__(256) void k4_gemm2(const unsigned short* __restrict__ zq,
                                                const unsigned short* __restrict__ proto_bf,
                                                const float* __restrict__ qnorm,
                                                const float* __restrict__ pnorm,
                                                float* __restrict__ out) {
  __shared__ unsigned short lA[128 * 32];
  __shared__ unsigned short lB[64 * 32];
  int tid = threadIdx.x;
  int r0 = blockIdx.x * 128;
  int wave = tid >> 6, lane = tid & 63;
  int lrow = lane & 15, lquad = lane >> 4;

  floatx4 acc[2][4];
#pragma unroll
  for (int i = 0; i < 2; i++)
#pragma unroll
    for (int j = 0; j < 4; j++) acc[i][j] = (floatx4){0.f, 0.f, 0.f, 0.f};

  int a_n = tid >> 2, a_k8 = (tid & 3) * 8;

  for (int k0 = 0; k0 < 512; k0 += 32) {
#pragma unroll
    for (int p = 0; p < 2; p++) {
      int row = p * 64 + a_n;
      *(float4*)&lA[row * 32 + a_k8] = *(const float4*)&zq[(size_t)(r0 + row) * 512 + k0 + a_k8];
    }
    *(float4*)&lB[a_n * 32 + a_k8] = *(const float4*)&proto_bf[(size_t)a_n * 512 + k0 + a_k8];
    __syncthreads();
    short8 af[2], bfr[4];
#pragma unroll
    for (int i = 0; i < 2; i++) af[i] = *(const short8*)&lA[(wave * 32 + i * 16 + lrow) * 32 + lquad * 8];
#pragma unroll
    for (int j = 0; j < 4; j++) bfr[j] = *(const short8*)&lB[(j * 16 + lrow) * 32 + lquad * 8];
#pragma unroll
    for (int i = 0; i < 2; i++)
#pragma unroll
      for (int j = 0; j < 4; j++)
        acc[i][j] = __builtin_amdgcn_mfma_f32_16x16x32_bf16(af[i], bfr[j], acc[i][j], 0, 0, 0);
    __syncthreads();
  }

#pragma unroll
  for (int i = 0; i < 2; i++) {
#pragma unroll
    for (int j = 0; j < 4; j++) {
      int col = j * 16 + lrow;
      float pn = pnorm[col];
#pragma unroll
      for (int r = 0; r < 4; r++) {
        int row = r0 + wave * 32 + i * 16 + lquad * 4 + r;
        out[(size_t)row * 64 + col] = 2.f * acc[i][j][r] - qnorm[row] - pn;
      }
    }
  }
}

extern "C" void kernel_launch(void* const* d_in, const int* in_sizes, int n_in,
                              void* d_out, int out_size, void* d_ws, size_t ws_size,
                              hipStream_t stream) {
  const float* xs = (const float*)d_in[0];
  const int* ys = (const int*)d_in[1];
  const float* xq = (const float*)d_in[2];
  const float* W = (const float*)d_in[3];
  const float* b = (const float*)d_in[4];
  float* out = (float*)d_out;
  char* ws = (char*)d_ws;

  size_t off = 0;
  auto take = [&](size_t bytes) -> char* {
    char* r = ws + off;
    off += (bytes + 255) & ~(size_t)255;
    return r;
  };
  unsigned short* Wt = (unsigned short*)take((size_t)D_DIM * F_DIM * 2);
  unsigned short* zq = (unsigned short*)take((size_t)Q_ROWS * D_DIM * 2);
  float* csum = (float*)take((size_t)NWAY * F_DIM * 4);
  unsigned short* proto_bf = (unsigned short*)take((size_t)NWAY * D_DIM * 2);
  float* qnorm = (float*)take((size_t)Q_ROWS * 4);
  float* counts = (float*)take(NWAY * 4);
  float* pnorm = (float*)take(NWAY * 4);
  int* order = (int*)take(S_ROWS * 4);
  int* starts = (int*)take((NWAY + 1) * 4);
  unsigned short* xqb = (unsigned short*)take((size_t)Q_ROWS * F_DIM * 2);
  bool fast = (off <= ws_size);   // launch-constant: graph-stable

  k0_transpose<<<256, 256, 0, stream>>>(W, Wt, qnorm);
  k0_sort<<<1, 256, 0, stream>>>(ys, order, starts, counts, pnorm);
  k1_csum<<<128, 256, 0, stream>>>(xs, order, starts, csum);
  k2_proto<<<128, 256, 0, stream>>>(W, b, csum, counts, proto_bf, pnorm);
  if (fast) {
    k_cvt<<<(Q_ROWS * F_DIM) / (256 * 8), 256, 0, stream>>>(xq, xqb);
    k3_gemm1_fast<<<512, 256, 0, stream>>>(xqb, Wt, b, zq, qnorm);
  } else {
    k3_gemm1<<<512, 256, 0, stream>>>(xq, Wt, b, zq, qnorm);
  }
  k4_gemm2<<<128, 256, 0, stream>>>(zq, proto_bf, qnorm, pnorm, out);
}

// Round 3
// 297.587 us; speedup vs baseline: 3.0844x; 1.2736x over previous
//
#include <hip/hip_runtime.h>

// ProtoNet: out[q][n] = -|| (xq[q]@W + b) - proto[n] ||^2
// proto[n] = (sum_{s: ys==n} xs[s]) @ W / max(cnt,1) + cnt*b/max(cnt,1)
// dist = qnorm[q] + pnorm[n] - 2*cross[q][n]; out = 2*cross - qnorm - pnorm.

typedef __attribute__((ext_vector_type(8))) short short8;
typedef __attribute__((ext_vector_type(4))) float floatx4;

#define S_ROWS 1024
#define F_DIM  2048
#define D_DIM  512
#define NWAY   64
#define Q_ROWS 16384

static __device__ __forceinline__ unsigned short f2bf(float f) {
  unsigned int u = __float_as_uint(f);
  u += 0x7FFF + ((u >> 16) & 1);   // RNE
  return (unsigned short)(u >> 16);
}
static __device__ __forceinline__ float bf2f(unsigned short s) {
  return __uint_as_float(((unsigned int)s) << 16);
}

// async global->LDS, 16B per lane. LDS dest = wave-uniform base + lane*16.
static __device__ __forceinline__ void load_lds16(const unsigned short* g, unsigned short* l) {
  __builtin_amdgcn_global_load_lds((const __attribute__((address_space(1))) unsigned int*)g,
                                   (__attribute__((address_space(3))) unsigned int*)l,
                                   16, 0, 0);
}

// ---- K0a: transpose W f32 [2048][512] -> Wt bf16 [512][2048];
//      zero qnorm[16384] and proto_acc[64*512] (256 blocks: 64 + 128 lanes) ----
__global__ __launch_bounds__(256) void k0_transpose(const float* __restrict__ W,
                                                    unsigned short* __restrict__ Wt,
                                                    float* __restrict__ qnorm,
                                                    float* __restrict__ proto_acc) {
  __shared__ unsigned short t[64][65];
  int bx = blockIdx.x;
  int f0 = (bx >> 3) << 6;   // 32 f-tiles
  int d0 = (bx & 7) << 6;    // 8 d-tiles
  for (int j = 0; j < 16; j++) {
    int lin = j * 256 + threadIdx.x;
    int fl = lin >> 6, dl = lin & 63;
    t[fl][dl] = f2bf(W[(size_t)(f0 + fl) * 512 + d0 + dl]);
  }
  __syncthreads();
  for (int j = 0; j < 16; j++) {
    int lin = j * 256 + threadIdx.x;
    int dl = lin >> 6, fl = lin & 63;
    Wt[(size_t)(d0 + dl) * 2048 + f0 + fl] = t[fl][dl];
  }
  int tid = threadIdx.x;
  if (tid < 64) qnorm[bx * 64 + tid] = 0.f;
  else if (tid < 192) proto_acc[bx * 128 + tid - 64] = 0.f;
}

// ---- K0b: bin support indices by class via LDS atomics (single block) ----
__global__ __launch_bounds__(256) void k0_sort(const int* __restrict__ ys,
                                               int* __restrict__ order,
                                               int* __restrict__ starts,
                                               float* __restrict__ counts) {
  __shared__ int cnt[NWAY];
  __shared__ int st[NWAY + 1];
  __shared__ int wp[NWAY];
  int tid = threadIdx.x;
  if (tid < NWAY) cnt[tid] = 0;
  __syncthreads();
  for (int j = tid; j < S_ROWS; j += 256) atomicAdd(&cnt[ys[j]], 1);
  __syncthreads();
  if (tid == 0) {
    int a = 0;
    for (int c = 0; c < NWAY; c++) { st[c] = a; wp[c] = a; a += cnt[c]; }
    st[NWAY] = a;
  }
  __syncthreads();
  for (int j = tid; j < S_ROWS; j += 256) {
    int c = ys[j];
    int p = atomicAdd(&wp[c], 1);
    order[p] = j;
  }
  if (tid < NWAY) counts[tid] = (float)cnt[tid];
  if (tid < NWAY + 1) starts[tid] = st[tid];
}

// ---- K1: class sums. grid = 64 classes x 2 f-tiles; float4 per thread ----
__global__ __launch_bounds__(256) void k1_csum(const float* __restrict__ xs,
                                               const int* __restrict__ order,
                                               const int* __restrict__ starts,
                                               float* __restrict__ csum) {
  __shared__ int lord[S_ROWS];
  int c = blockIdx.x >> 1;
  int tid = threadIdx.x;
  int s = starts[c], e = starts[c + 1];
  int len = e - s;
  for (int j = tid; j < len; j += 256) lord[j] = order[s + j];
  __syncthreads();
  int f0 = (blockIdx.x & 1) * 1024 + tid * 4;
  float4 a = {0.f, 0.f, 0.f, 0.f};
  for (int i = 0; i < len; i++) {
    float4 v = *(const float4*)&xs[(size_t)lord[i] * F_DIM + f0];
    a.x += v.x; a.y += v.y; a.z += v.z; a.w += v.w;
  }
  *(float4*)&csum[(size_t)c * F_DIM + f0] = a;
}

// ---- K2: partial proto: grid = 64 classes x 2 d-halves x 8 f-chunks = 1024 blocks.
//      proto_acc[c][d] += sum_{f in chunk} csum[c][f] * W[f][d]  (f32 atomics) ----
__global__ __launch_bounds__(256) void k2_proto(const float* __restrict__ W,
                                               const float* __restrict__ csum,
                                               float* __restrict__ proto_acc) {
  __shared__ float cs[256];
  int bx = blockIdx.x;
  int c = bx >> 4;
  int dh = ((bx >> 3) & 1) * 256;
  int fc = (bx & 7) * 256;
  int tid = threadIdx.x;
  cs[tid] = csum[(size_t)c * F_DIM + fc + tid];
  __syncthreads();
  float a0 = 0.f;
#pragma unroll 8
  for (int f = 0; f < 256; f++)
    a0 += cs[f] * W[(size_t)(fc + f) * 512 + dh + tid];
  atomicAdd(&proto_acc[c * 512 + dh + tid], a0);
}

// ---- K2b: finalize proto: scale, +bias, bf16, pnorm. grid = 64 classes ----
__global__ __launch_bounds__(256) void k2b_finalize(const float* __restrict__ proto_acc,
                                                    const float* __restrict__ b,
                                                    const float* __restrict__ counts,
                                                    unsigned short* __restrict__ proto_bf,
                                                    float* __restrict__ pnorm) {
  __shared__ float red[256];
  int n = blockIdx.x, tid = threadIdx.x;
  float cntv = counts[n];
  float inv = 1.f / fmaxf(cntv, 1.f);
  float acc = 0.f;
#pragma unroll
  for (int h = 0; h < 2; h++) {
    int d = h * 256 + tid;
    float p = (proto_acc[n * 512 + d] + cntv * b[d]) * inv;
    unsigned short hh = f2bf(p);
    proto_bf[(size_t)n * 512 + d] = hh;
    float q = bf2f(hh);
    acc += q * q;
  }
  red[tid] = acc;
  __syncthreads();
  for (int s = 128; s > 0; s >>= 1) {
    if (tid < s) red[tid] += red[tid + s];
    __syncthreads();
  }
  if (tid == 0) pnorm[n] = red[0];
}

// ---- Kcvt: xq f32 -> bf16, 8 elems/thread ----
__global__ __launch_bounds__(256) void k_cvt(const float* __restrict__ xq,
                                             unsigned short* __restrict__ xqb) {
  size_t i = ((size_t)blockIdx.x * 256 + threadIdx.x) * 8;
  float4 v0 = *(const float4*)&xq[i];
  float4 v1 = *(const float4*)&xq[i + 4];
  ushort4 w0, w1;
  w0.x = f2bf(v0.x); w0.y = f2bf(v0.y); w0.z = f2bf(v0.z); w0.w = f2bf(v0.w);
  w1.x = f2bf(v1.x); w1.y = f2bf(v1.y); w1.z = f2bf(v1.z); w1.w = f2bf(v1.w);
  *(ushort4*)&xqb[i] = w0;
  *(ushort4*)&xqb[i + 4] = w1;
}

// ---- K3 fast: z_q = xqb@Wt^T + b, bf16 MFMA 128x128xBK32, global_load_lds staging ----
__global__ __launch_bounds__(256) void k3_gemm1_fast(const unsigned short* __restrict__ xqb,
                                                     const unsigned short* __restrict__ Wt,
                                                     const float* __restrict__ b,
                                                     unsigned short* __restrict__ zq,
                                                     float* __restrict__ qnorm) {
  __shared__ __align__(16) unsigned short lA[128 * 32];
  __shared__ __align__(16) unsigned short lB[128 * 32];
  int tid = threadIdx.x;
  int bx = blockIdx.x;
  int n0 = (bx & 3) * 128;
  int m0 = (bx >> 2) * 128;
  int wave = tid >> 6, lane = tid & 63;
  int wm = (wave & 1) * 64, wn = (wave >> 1) * 64;
  int lrow = lane & 15, lquad = lane >> 4;

  floatx4 acc[4][4];
#pragma unroll
  for (int i = 0; i < 4; i++)
#pragma unroll
    for (int j = 0; j < 4; j++) acc[i][j] = (floatx4){0.f, 0.f, 0.f, 0.f};

  int c0 = wave * 64 + lane;      // base chunk id; chunk covers 16B = 8 halfs

  for (int k0 = 0; k0 < F_DIM; k0 += 32) {
#pragma unroll
    for (int i = 0; i < 2; i++) {
      int c = i * 256 + c0;
      int row = c >> 2, k8 = (c & 3) * 8;
      load_lds16(&xqb[(size_t)(m0 + row) * F_DIM + k0 + k8],
                 &lA[(size_t)(i * 256 + wave * 64) * 8]);
      load_lds16(&Wt[(size_t)(n0 + row) * F_DIM + k0 + k8],
                 &lB[(size_t)(i * 256 + wave * 64) * 8]);
    }
    __syncthreads();
    short8 af[4], bfr[4];
#pragma unroll
    for (int i = 0; i < 4; i++) af[i] = *(const short8*)&lA[(wm + i * 16 + lrow) * 32 + lquad * 8];
#pragma unroll
    for (int j = 0; j < 4; j++) bfr[j] = *(const short8*)&lB[(wn + j * 16 + lrow) * 32 + lquad * 8];
#pragma unroll
    for (int i = 0; i < 4; i++)
#pragma unroll
      for (int j = 0; j < 4; j++)
        acc[i][j] = __builtin_amdgcn_mfma_f32_16x16x32_bf16(af[i], bfr[j], acc[i][j], 0, 0, 0);
    __syncthreads();
  }

#pragma unroll
  for (int i = 0; i < 4; i++) {
    float rn[4] = {0.f, 0.f, 0.f, 0.f};
#pragma unroll
    for (int j = 0; j < 4; j++) {
      int col = n0 + wn + j * 16 + lrow;
      float bb = b[col];
#pragma unroll
      for (int r = 0; r < 4; r++) {
        int row = m0 + wm + i * 16 + lquad * 4 + r;
        float v = acc[i][j][r] + bb;
        unsigned short h = f2bf(v);
        zq[(size_t)row * 512 + col] = h;
        float vq = bf2f(h);
        rn[r] += vq * vq;
      }
    }
#pragma unroll
    for (int r = 0; r < 4; r++) {
      float s = rn[r];
      s += __shfl_xor(s, 1, 16);
      s += __shfl_xor(s, 2, 16);
      s += __shfl_xor(s, 4, 16);
      s += __shfl_xor(s, 8, 16);
      if (lrow == 0) {
        int row = m0 + wm + i * 16 + lquad * 4 + r;
        atomicAdd(&qnorm[row], s);
      }
    }
  }
}

// ---- K3 fallback: f32 A with in-kernel conversion (used if ws too small) ----
__global__ __launch_bounds__(256) void k3_gemm1(const float* __restrict__ xq,
                                                const unsigned short* __restrict__ Wt,
                                                const float* __restrict__ b,
                                                unsigned short* __restrict__ zq,
                                                float* __restrict__ qnorm) {
  __shared__ unsigned short lA[128 * 32];
  __shared__ unsigned short lB[128 * 32];
  int tid = threadIdx.x;
  int bx = blockIdx.x;
  int n0 = (bx & 3) * 128;
  int m0 = (bx >> 2) * 128;
  int wave = tid >> 6, lane = tid & 63;
  int wm = (wave & 1) * 64, wn = (wave >> 1) * 64;
  int lrow = lane & 15, lquad = lane >> 4;

  floatx4 acc[4][4];
#pragma unroll
  for (int i = 0; i < 4; i++)
#pragma unroll
    for (int j = 0; j < 4; j++) acc[i][j] = (floatx4){0.f, 0.f, 0.f, 0.f};

  int a_row = tid >> 3, a_kq = tid & 7;
  int b_n = tid >> 2, b_k8 = (tid & 3) * 8;

  for (int k0 = 0; k0 < F_DIM; k0 += 32) {
#pragma unroll
    for (int p = 0; p < 4; p++) {
      int row = p * 32 + a_row;
      float4 v = *(const float4*)&xq[(size_t)(m0 + row) * F_DIM + k0 + a_kq * 4];
      ushort4 w;
      w.x = f2bf(v.x); w.y = f2bf(v.y); w.z = f2bf(v.z); w.w = f2bf(v.w);
      *(ushort4*)&lA[row * 32 + a_kq * 4] = w;
    }
#pragma unroll
    for (int p = 0; p < 2; p++) {
      int n = p * 64 + b_n;
      *(float4*)&lB[n * 32 + b_k8] = *(const float4*)&Wt[(size_t)(n0 + n) * 2048 + k0 + b_k8];
    }
    __syncthreads();
    short8 af[4], bfr[4];
#pragma unroll
    for (int i = 0; i < 4; i++) af[i] = *(const short8*)&lA[(wm + i * 16 + lrow) * 32 + lquad * 8];
#pragma unroll
    for (int j = 0; j < 4; j++) bfr[j] = *(const short8*)&lB[(wn + j * 16 + lrow) * 32 + lquad * 8];
#pragma unroll
    for (int i = 0; i < 4; i++)
#pragma unroll
      for (int j = 0; j < 4; j++)
        acc[i][j] = __builtin_amdgcn_mfma_f32_16x16x32_bf16(af[i], bfr[j], acc[i][j], 0, 0, 0);
    __syncthreads();
  }

#pragma unroll
  for (int i = 0; i < 4; i++) {
    float rn[4] = {0.f, 0.f, 0.f, 0.f};
#pragma unroll
    for (int j = 0; j < 4; j++) {
      int col = n0 + wn + j * 16 + lrow;
      float bb = b[col];
#pragma unroll
      for (int r = 0; r < 4; r++) {
        int row = m0 + wm + i * 16 + lquad * 4 + r;
        float v = acc[i][j][r] + bb;
        unsigned short h = f2bf(v);
        zq[(size_t)row * 512 + col] = h;
        float vq = bf2f(h);
        rn[r] += vq * vq;
      }
    }
#pragma unroll
    for (int r = 0; r < 4; r++) {
      float s = rn[r];
      s += __shfl_xor(s, 1, 16);
      s += __shfl_xor(s, 2, 16);
      s += __shfl_xor(s, 4, 16);
      s += __shfl_xor(s, 8, 16);
      if (lrow == 0) {
        int row = m0 + wm + i * 16 + lquad * 4 + r;
        atomicAdd(&qnorm[row], s);
      }
    }
  }
}

// ---- K4: cross = zq @ proto^T; out = 2*cross - qnorm - pnorm ----
__global__ __launch_bounds__(256) void k4_gemm2(const unsigned short* __restrict__ zq,
                                                const unsigned short* __restrict__ proto_bf,
                                                const float* __restrict__ qnorm,
                                                const float* __restrict__ pnorm,
                                                float* __restrict__ out) {
  __shared__ unsigned short lA[128 * 32];
  __shared__ unsigned short lB[64 * 32];
  int tid = threadIdx.x;
  int r0 = blockIdx.x * 128;
  int wave = tid >> 6, lane = tid & 63;
  int lrow = lane & 15, lquad = lane >> 4;

  floatx4 acc[2][4];
#pragma unroll
  for (int i = 0; i < 2; i++)
#pragma unroll
    for (int j = 0; j < 4; j++) acc[i][j] = (floatx4){0.f, 0.f, 0.f, 0.f};

  int a_n = tid >> 2, a_k8 = (tid & 3) * 8;

  for (int k0 = 0; k0 < 512; k0 += 32) {
#pragma unroll
    for (int p = 0; p < 2; p++) {
      int row = p * 64 + a_n;
      *(float4*)&lA[row * 32 + a_k8] = *(const float4*)&zq[(size_t)(r0 + row) * 512 + k0 + a_k8];
    }
    *(float4*)&lB[a_n * 32 + a_k8] = *(const float4*)&proto_bf[(size_t)a_n * 512 + k0 + a_k8];
    __syncthreads();
    short8 af[2], bfr[4];
#pragma unroll
    for (int i = 0; i < 2; i++) af[i] = *(const short8*)&lA[(wave * 32 + i * 16 + lrow) * 32 + lquad * 8];
#pragma unroll
    for (int j = 0; j < 4; j++) bfr[j] = *(const short8*)&lB[(j * 16 + lrow) * 32 + lquad * 8];
#pragma unroll
    for (int i = 0; i < 2; i++)
#pragma unroll
      for (int j = 0; j < 4; j++)
        acc[i][j] = __builtin_amdgcn_mfma_f32_16x16x32_bf16(af[i], bfr[j], acc[i][j], 0, 0, 0);
    __syncthreads();
  }

#pragma unroll
  for (int i = 0; i < 2; i++) {
#pragma unroll
    for (int j = 0; j < 4; j++) {
      int col = j * 16 + lrow;
      float pn = pnorm[col];
#pragma unroll
      for (int r = 0; r < 4; r++) {
        int row = r0 + wave * 32 + i * 16 + lquad * 4 + r;
        out[(size_t)row * 64 + col] = 2.f * acc[i][j][r] - qnorm[row] - pn;
      }
    }
  }
}

extern "C" void kernel_launch(void* const* d_in, const int* in_sizes, int n_in,
                              void* d_out, int out_size, void* d_ws, size_t ws_size,
                              hipStream_t stream) {
  const float* xs = (const float*)d_in[0];
  const int* ys = (const int*)d_in[1];
  const float* xq = (const float*)d_in[2];
  const float* W = (const float*)d_in[3];
  const float* b = (const float*)d_in[4];
  float* out = (float*)d_out;
  char* ws = (char*)d_ws;

  size_t off = 0;
  auto take = [&](size_t bytes) -> char* {
    char* r = ws + off;
    off += (bytes + 255) & ~(size_t)255;
    return r;
  };
  unsigned short* Wt = (unsigned short*)take((size_t)D_DIM * F_DIM * 2);
  unsigned short* zq = (unsigned short*)take((size_t)Q_ROWS * D_DIM * 2);
  float* csum = (float*)take((size_t)NWAY * F_DIM * 4);
  float* proto_acc = (float*)take((size_t)NWAY * D_DIM * 4);
  unsigned short* proto_bf = (unsigned short*)take((size_t)NWAY * D_DIM * 2);
  float* qnorm = (float*)take((size_t)Q_ROWS * 4);
  float* counts = (float*)take(NWAY * 4);
  float* pnorm = (float*)take(NWAY * 4);
  int* order = (int*)take(S_ROWS * 4);
  int* starts = (int*)take((NWAY + 1) * 4);
  unsigned short* xqb = (unsigned short*)take((size_t)Q_ROWS * F_DIM * 2);
  bool fast = (off <= ws_size);   // launch-constant: graph-stable

  k0_transpose<<<256, 256, 0, stream>>>(W, Wt, qnorm, proto_acc);
  k0_sort<<<1, 256, 0, stream>>>(ys, order, starts, counts);
  k1_csum<<<128, 256, 0, stream>>>(xs, order, starts, csum);
  k2_proto<<<1024, 256, 0, stream>>>(W, csum, proto_acc);
  k2b_finalize<<<64, 256, 0, stream>>>(proto_acc, b, counts, proto_bf, pnorm);
  if (fast) {
    k_cvt<<<(Q_ROWS * F_DIM) / (256 * 8), 256, 0, stream>>>(xq, xqb);
    k3_gemm1_fast<<<512, 256, 0, stream>>>(xqb, Wt, b, zq, qnorm);
  } else {
    k3_gemm1<<<512, 256, 0, stream>>>(xq, Wt, b, zq, qnorm);
  }
  k4_gemm2<<<128, 256, 0, stream>>>(zq, proto_bf, qnorm, pnorm, out);
}